// Round 9
// baseline (185.185 us; speedup 1.0000x reference)
//
#include <hip/hip_runtime.h>
#include <hip/hip_bf16.h>

#define DIM 128
#define KNB 16

using fragAB = __attribute__((ext_vector_type(8))) short;   // 8 bf16 (4 VGPRs)
using f32x4  = __attribute__((ext_vector_type(4))) float;   // 4 fp32 acc
using u32x4  = __attribute__((ext_vector_type(4))) unsigned int;

union frag_u { fragAB s; u32x4 u; };

__device__ __forceinline__ unsigned short bf16bits(float f) {
    union { float f; unsigned u; } v; v.f = f;
    unsigned r = v.u + 0x7fffu + ((v.u >> 16) & 1u);   // round-nearest-even
    return (unsigned short)(r >> 16);
}
// packed f32x2 -> bf16x2 in one HW inst (RNE); no builtin on gfx950 (m240)
__device__ __forceinline__ unsigned cvt_pk_bf16(float lo, float hi) {
    unsigned r;
    asm("v_cvt_pk_bf16_f32 %0, %1, %2" : "=v"(r) : "v"(lo), "v"(hi));
    return r;
}
__device__ __forceinline__ float bflo(unsigned u) { return __uint_as_float(u << 16); }
__device__ __forceinline__ float bfhi(unsigned u) { return __uint_as_float(u & 0xffff0000u); }

// ---------------------------------------------------------------------------
// W1T pack (bf16) + W2 bf16. W1T[h'][d]: h'<128 -> W1[d][h'] (A-part),
// h'>=128 -> W1[128+d][h'-128] (B-part).
// ---------------------------------------------------------------------------
__global__ __launch_bounds__(256) void na_w1t(
    const float* __restrict__ W1, const float* __restrict__ W2,
    unsigned short* __restrict__ W1T, unsigned short* __restrict__ W2b)
{
    int idx = blockIdx.x * 256 + threadIdx.x;   // 0..32767 = h'*128 + d
    int hp = idx >> 7, d = idx & 127;
    float v = (hp < DIM) ? W1[(size_t)d * DIM + hp]
                         : W1[(size_t)(DIM + d) * DIM + (hp - DIM)];
    W1T[idx] = bf16bits(v);
    if (blockIdx.x == 0 && threadIdx.x < DIM) W2b[threadIdx.x] = bf16bits(W2[threadIdx.x]);
}

// ---------------------------------------------------------------------------
// lat -> bf16 streaming pre-pass, written directly into P's lat-half.
// Thread t: node n = t>>4, chunk c = t&15 (8 f32 in, 16B bf16 out).
// ---------------------------------------------------------------------------
__global__ __launch_bounds__(256) void na_lat2bf(
    const float* __restrict__ lat, unsigned short* __restrict__ P, int nNodes)
{
    int t = blockIdx.x * 256 + threadIdx.x;
    if (t >= nNodes * 16) return;
    int n = t >> 4, c = t & 15;
    const float* src = lat + (size_t)n * DIM + c * 8;
    f32x4 lo = *(const f32x4*)src;
    f32x4 hi = *(const f32x4*)(src + 4);
    u32x4 pk;
    pk[0] = cvt_pk_bf16(lo[0], lo[1]);
    pk[1] = cvt_pk_bf16(lo[2], lo[3]);
    pk[2] = cvt_pk_bf16(hi[0], hi[1]);
    pk[3] = cvt_pk_bf16(hi[2], hi[3]);
    *(u32x4*)(P + (size_t)n * 256 + DIM + c * 8) = pk;
}

// ---------------------------------------------------------------------------
// Phase 1 (MFMA, swapped operands, 32 rows/wave, bf16 inputs from P):
//   D = W1tile(16 h' x K) . latT(K x 16 nodes); D col = node, row = h'.
// B-operand frags load DIRECTLY from P's bf16 lat-half (no f32 read, no cvt).
// Two node-sets share each W1T A-frag load (1 load : 2 MFMA).
//   Ab[n][h]      = bf16( b1[h] + lat[n]·W1top[:,h] )
//   P[n][0..128)  = bf16( lat[n]·W1bot[:,h] )
// ---------------------------------------------------------------------------
__global__ __launch_bounds__(256) void na_precompute_mfma(
    const unsigned short* __restrict__ Pu, const unsigned short* __restrict__ W1T,
    const float* __restrict__ b1, unsigned short* __restrict__ Ab,
    unsigned short* __restrict__ P, int nNodes)
{
    const int wave = threadIdx.x >> 6;
    const int lane = threadIdx.x & 63;
    const int lg = lane >> 4, lr = lane & 15;
    const int mbase = blockIdx.x * 128 + wave * 32;

    f32x4 acc0[16], acc1[16];
#pragma unroll
    for (int i = 0; i < 16; ++i) {
        acc0[i] = (f32x4){0.f, 0.f, 0.f, 0.f};
        acc1[i] = (f32x4){0.f, 0.f, 0.f, 0.f};
    }

    const int r0 = mbase + lr;
    const int r1 = mbase + 16 + lr;
    const bool v0 = r0 < nNodes, v1 = r1 < nNodes;
    const unsigned short* q0 = Pu + (size_t)(v0 ? r0 : (nNodes - 1)) * 256 + DIM;
    const unsigned short* q1 = Pu + (size_t)(v1 ? r1 : (nNodes - 1)) * 256 + DIM;

    fragAB bl0[4], bl1[4];
#pragma unroll
    for (int ks = 0; ks < 4; ++ks) {
        bl0[ks] = *(const fragAB*)(q0 + ks * 32 + lg * 8);
        bl1[ks] = *(const fragAB*)(q1 + ks * 32 + lg * 8);
    }

#pragma unroll
    for (int ks = 0; ks < 4; ++ks) {
#pragma unroll
        for (int nt = 0; nt < 16; ++nt) {
            fragAB af = *(const fragAB*)(W1T + (size_t)(nt * 16 + lr) * DIM + ks * 32 + lg * 8);
            acc0[nt] = __builtin_amdgcn_mfma_f32_16x16x32_bf16(af, bl0[ks], acc0[nt], 0, 0, 0);
            acc1[nt] = __builtin_amdgcn_mfma_f32_16x16x32_bf16(af, bl1[ks], acc1[nt], 0, 0, 0);
        }
    }

    if (v0) {
        unsigned short* arow = Ab + (size_t)r0 * DIM;
        unsigned short* prow = P  + (size_t)r0 * 256;
#pragma unroll
        for (int nt = 0; nt < 8; ++nt) {
            float4 bv = *(const float4*)(b1 + nt * 16 + lg * 4);
            uint2 pk;
            pk.x = cvt_pk_bf16(acc0[nt][0] + bv.x, acc0[nt][1] + bv.y);
            pk.y = cvt_pk_bf16(acc0[nt][2] + bv.z, acc0[nt][3] + bv.w);
            *(uint2*)(arow + nt * 16 + lg * 4) = pk;
        }
#pragma unroll
        for (int nt = 8; nt < 16; ++nt) {
            uint2 pk;
            pk.x = cvt_pk_bf16(acc0[nt][0], acc0[nt][1]);
            pk.y = cvt_pk_bf16(acc0[nt][2], acc0[nt][3]);
            *(uint2*)(prow + (nt - 8) * 16 + lg * 4) = pk;
        }
    }
    if (v1) {
        unsigned short* arow = Ab + (size_t)r1 * DIM;
        unsigned short* prow = P  + (size_t)r1 * 256;
#pragma unroll
        for (int nt = 0; nt < 8; ++nt) {
            float4 bv = *(const float4*)(b1 + nt * 16 + lg * 4);
            uint2 pk;
            pk.x = cvt_pk_bf16(acc1[nt][0] + bv.x, acc1[nt][1] + bv.y);
            pk.y = cvt_pk_bf16(acc1[nt][2] + bv.z, acc1[nt][3] + bv.w);
            *(uint2*)(arow + nt * 16 + lg * 4) = pk;
        }
#pragma unroll
        for (int nt = 8; nt < 16; ++nt) {
            uint2 pk;
            pk.x = cvt_pk_bf16(acc1[nt][0], acc1[nt][1]);
            pk.y = cvt_pk_bf16(acc1[nt][2], acc1[nt][3]);
            *(uint2*)(prow + (nt - 8) * 16 + lg * 4) = pk;
        }
    }
}

// ---------------------------------------------------------------------------
// Phase 2: one wave per node. Scores via MFMA (W2 replicated over B-cols),
// exp 4/lane + butterfly distribution, weighted aggregation of lat rows.
// Gather-service-bound floor (R6 MLP-doubling test: flat; ~8x490 GB/s
// per-XCD L2-miss service, bytes compulsory at bf16 precision).
// ---------------------------------------------------------------------------
__global__ __launch_bounds__(256) void na_score_agg(
    const int* __restrict__ nbr, const unsigned short* __restrict__ Ab,
    const unsigned short* __restrict__ Pu, const unsigned int* __restrict__ P32,
    const unsigned short* __restrict__ W2b, float* __restrict__ out, int nNodes)
{
    const int wave = threadIdx.x >> 6;
    const int lane = threadIdx.x & 63;
    const int lg = lane >> 4, lr = lane & 15;
    const int n = blockIdx.x * 4 + wave;
    if (n >= nNodes) return;

    const int jl = nbr[n * KNB + lr];          // lane's neighbor (k = lr)

    // B-half gathers: lane reads 16B of row j_lr per ks (A-frag layout for H)
    frag_u fB[4];
    const unsigned short* Pj = Pu + (size_t)jl * 256;
#pragma unroll
    for (int ks = 0; ks < 4; ++ks)
        fB[ks].s = *(const fragAB*)(Pj + ks * 32 + lg * 8);

    // lat-half gathers: lane owns dims (2l,2l+1), loop over k
    unsigned bL[KNB];
#pragma unroll
    for (int k = 0; k < KNB; ++k) {
        int j = __shfl(jl, k);
        bL[k] = P32[(size_t)j * 128 + 64 + lane];
    }

    // own A row + replicated-W2 B-frags (cache-hot)
    frag_u fA[4]; fragAB fW[4];
    const unsigned short* An = Ab + (size_t)n * DIM;
#pragma unroll
    for (int ks = 0; ks < 4; ++ks) {
        fA[ks].s = *(const fragAB*)(An + ks * 32 + lg * 8);
        fW[ks]   = *(const fragAB*)(W2b + ks * 32 + lg * 8);
    }

    // H build (bf16) + MFMA score chain
    f32x4 accS = (f32x4){0.f, 0.f, 0.f, 0.f};
#pragma unroll
    for (int ks = 0; ks < 4; ++ks) {
        u32x4 alo = fA[ks].u << 16, ahi = fA[ks].u & 0xffff0000u;
        u32x4 blo = fB[ks].u << 16, bhi = fB[ks].u & 0xffff0000u;
        frag_u h;
#pragma unroll
        for (int p = 0; p < 4; ++p) {
            float h0 = fmaxf(__uint_as_float(alo[p]) + __uint_as_float(blo[p]), 0.f);
            float h1 = fmaxf(__uint_as_float(ahi[p]) + __uint_as_float(bhi[p]), 0.f);
            h.u[p] = cvt_pk_bf16(h0, h1);
        }
        accS = __builtin_amdgcn_mfma_f32_16x16x32_bf16(h.s, fW[ks], accS, 0, 0, 0);
    }
    // lane holds S[lg*4+r] in accS[r] (replicated across lr)

    // softmax: global max, 4 exps per lane, distribute e across lg groups
    float m = fmaxf(fmaxf(accS[0], accS[1]), fmaxf(accS[2], accS[3]));
    m = fmaxf(m, __shfl_xor(m, 16));
    m = fmaxf(m, __shfl_xor(m, 32));

    float e4[4];
#pragma unroll
    for (int r = 0; r < 4; ++r) e4[r] = __expf(accS[r] - m);

    float sum = e4[0] + e4[1] + e4[2] + e4[3];
    sum += __shfl_xor(sum, 16);
    sum += __shfl_xor(sum, 32);
    const float inv = 1.f / sum;

    const bool hi1 = lg & 1, hi2 = lg & 2;
    float o4[4];
#pragma unroll
    for (int r = 0; r < 4; ++r) o4[r] = __shfl_xor(e4[r], 16);
    float v8[8];
#pragma unroll
    for (int r = 0; r < 4; ++r) {
        v8[r]     = hi1 ? o4[r] : e4[r];
        v8[4 + r] = hi1 ? e4[r] : o4[r];
    }
    float o8[8];
#pragma unroll
    for (int i = 0; i < 8; ++i) o8[i] = __shfl_xor(v8[i], 32);
    float e[KNB];
#pragma unroll
    for (int i = 0; i < 8; ++i) {
        e[i]     = hi2 ? o8[i] : v8[i];
        e[8 + i] = hi2 ? v8[i] : o8[i];
    }

    // weighted aggregation
    float o0 = 0.f, o1 = 0.f;
#pragma unroll
    for (int k = 0; k < KNB; ++k) {
        o0 += e[k] * bflo(bL[k]);
        o1 += e[k] * bfhi(bL[k]);
    }

    float2 o; o.x = o0 * inv; o.y = o1 * inv;
    *(float2*)(out + (size_t)n * DIM + 2 * lane) = o;
}

// ---------------------------------------------------------------------------
// Fallback (workspace too small): direct computation, one wave/node.
// ---------------------------------------------------------------------------
__global__ __launch_bounds__(256) void na_naive(
    const float* __restrict__ lat, const int* __restrict__ nbr,
    const float* __restrict__ W1, const float* __restrict__ b1,
    const float* __restrict__ W2, float* __restrict__ out, int nNodes)
{
    const int wave = threadIdx.x >> 6;
    const int lane = threadIdx.x & 63;
    const int n = blockIdx.x * 4 + wave;
    if (n >= nNodes) return;

    const int d0 = lane, d1 = lane + 64;
    const float w20 = W2[d0];
    const float w21 = W2[d1];
    const float c0 = lat[(size_t)n * DIM + d0];
    const float c1 = lat[(size_t)n * DIM + d1];

    float a0 = b1[d0], a1 = b1[d1];
    for (int r = 0; r < DIM; ++r) {
        float cv = (r < 64) ? __shfl(c0, r) : __shfl(c1, r - 64);
        a0 += cv * W1[(size_t)r * DIM + d0];
        a1 += cv * W1[(size_t)r * DIM + d1];
    }

    const int jl = nbr[n * KNB + (lane & 15)];
    float s[KNB], nl0[KNB], nl1[KNB];

    for (int k = 0; k < KNB; ++k) {
        int j = __shfl(jl, k);
        float l0 = lat[(size_t)j * DIM + d0];
        float l1 = lat[(size_t)j * DIM + d1];
        nl0[k] = l0; nl1[k] = l1;
        float h0 = a0, h1 = a1;
        for (int r = 0; r < DIM; ++r) {
            float nv = (r < 64) ? __shfl(l0, r) : __shfl(l1, r - 64);
            h0 += nv * W1[(size_t)(DIM + r) * DIM + d0];
            h1 += nv * W1[(size_t)(DIM + r) * DIM + d1];
        }
        h0 = fmaxf(h0, 0.f);
        h1 = fmaxf(h1, 0.f);
        float p = h0 * w20 + h1 * w21;
#pragma unroll
        for (int off = 32; off; off >>= 1) p += __shfl_xor(p, off);
        s[k] = p;
    }

    float m = s[0];
#pragma unroll
    for (int k = 1; k < KNB; ++k) m = fmaxf(m, s[k]);
    float sum = 0.f;
#pragma unroll
    for (int k = 0; k < KNB; ++k) { s[k] = expf(s[k] - m); sum += s[k]; }
    float inv = 1.f / sum;

    float o0 = 0.f, o1 = 0.f;
#pragma unroll
    for (int k = 0; k < KNB; ++k) { o0 += s[k] * nl0[k]; o1 += s[k] * nl1[k]; }

    out[(size_t)n * DIM + d0] = o0 * inv;
    out[(size_t)n * DIM + d1] = o1 * inv;
}

extern "C" void kernel_launch(void* const* d_in, const int* in_sizes, int n_in,
                              void* d_out, int out_size, void* d_ws, size_t ws_size,
                              hipStream_t stream)
{
    const float* lat = (const float*)d_in[0];
    const int*   nbr = (const int*)  d_in[1];
    const float* W1  = (const float*)d_in[2];
    const float* b1  = (const float*)d_in[3];
    const float* W2  = (const float*)d_in[4];
    // d_in[5] = b2: shift-invariant under softmax, unused.
    float* out = (float*)d_out;

    const int nNodes = in_sizes[0] / DIM;  // 100000
    const size_t bytesAb = (size_t)nNodes * DIM * sizeof(unsigned short); // 25.6 MB
    const size_t bytesP  = (size_t)nNodes * 256 * sizeof(unsigned short); // 51.2 MB
    const size_t bytesW  = (256 * DIM + DIM) * sizeof(unsigned short);    // 64.25 KiB

    if (ws_size >= bytesAb + bytesP + bytesW) {
        unsigned short* Ab  = (unsigned short*)d_ws;
        unsigned short* P   = (unsigned short*)((char*)d_ws + bytesAb);
        unsigned short* W1T = (unsigned short*)((char*)d_ws + bytesAb + bytesP);
        unsigned short* W2b = W1T + 256 * DIM;
        na_w1t<<<128, 256, 0, stream>>>(W1, W2, W1T, W2b);
        na_lat2bf<<<(nNodes * 16 + 255) / 256, 256, 0, stream>>>(lat, P, nNodes);
        na_precompute_mfma<<<(nNodes + 127) / 128, 256, 0, stream>>>(P, W1T, b1, Ab, P, nNodes);
        na_score_agg<<<(nNodes + 3) / 4, 256, 0, stream>>>(nbr, Ab, P, (const unsigned int*)P, W2b, out, nNodes);
    } else {
        na_naive<<<(nNodes + 3) / 4, 256, 0, stream>>>(lat, nbr, W1, b1, W2, out, nNodes);
    }
}

// Round 10
// 161.769 us; speedup vs baseline: 1.1447x; 1.1447x over previous
//
#include <hip/hip_runtime.h>
#include <hip/hip_bf16.h>

#define DIM 128
#define KNB 16

using fragAB = __attribute__((ext_vector_type(8))) short;   // 8 bf16 (4 VGPRs)
using f32x4  = __attribute__((ext_vector_type(4))) float;   // 4 fp32 acc
using u32x4  = __attribute__((ext_vector_type(4))) unsigned int;

union frag_u { fragAB s; u32x4 u; };

__device__ __forceinline__ unsigned short bf16bits(float f) {
    union { float f; unsigned u; } v; v.f = f;
    unsigned r = v.u + 0x7fffu + ((v.u >> 16) & 1u);   // round-nearest-even
    return (unsigned short)(r >> 16);
}
// packed f32x2 -> bf16x2 in one HW inst (RNE); no builtin on gfx950 (m240)
__device__ __forceinline__ unsigned cvt_pk_bf16(float lo, float hi) {
    unsigned r;
    asm("v_cvt_pk_bf16_f32 %0, %1, %2" : "=v"(r) : "v"(lo), "v"(hi));
    return r;
}
__device__ __forceinline__ float bflo(unsigned u) { return __uint_as_float(u << 16); }
__device__ __forceinline__ float bfhi(unsigned u) { return __uint_as_float(u & 0xffff0000u); }

// ---------------------------------------------------------------------------
// W1T pack (bf16) + W2 bf16. W1T[h'][d]: h'<128 -> W1[d][h'] (A-part),
// h'>=128 -> W1[128+d][h'-128] (B-part).
// ---------------------------------------------------------------------------
__global__ __launch_bounds__(256) void na_w1t(
    const float* __restrict__ W1, const float* __restrict__ W2,
    unsigned short* __restrict__ W1T, unsigned short* __restrict__ W2b)
{
    int idx = blockIdx.x * 256 + threadIdx.x;   // 0..32767 = h'*128 + d
    int hp = idx >> 7, d = idx & 127;
    float v = (hp < DIM) ? W1[(size_t)d * DIM + hp]
                         : W1[(size_t)(DIM + d) * DIM + (hp - DIM)];
    W1T[idx] = bf16bits(v);
    if (blockIdx.x == 0 && threadIdx.x < DIM) W2b[threadIdx.x] = bf16bits(W2[threadIdx.x]);
}

// ---------------------------------------------------------------------------
// Phase 1 (MFMA, swapped operands, 32 rows/wave, W1T staged in LDS):
//   D = W1tile(16 h' x K) . latT(K x 16 nodes); D col = node, row = h'.
// W1T (64KB) staged once per block into LDS with XOR swizzle
// (byte ^= (row&7)<<4, the G4-verified fix for 16-row x b128 reads), then
// all A-frags come from ds_read_b128 -- no L1 thrash, imm-foldable offsets.
// Two node-sets share each A-frag (1 ds_read : 2 MFMA).
//   Ab[n][h]      = bf16( b1[h] + lat[n]·W1top[:,h] )
//   P[n][0..128)  = bf16( lat[n]·W1bot[:,h] )
//   P[n][128..256)= bf16( lat[n] )   <- from held B-frags, no re-read
// ---------------------------------------------------------------------------
__global__ __launch_bounds__(256) void na_precompute_mfma(
    const float* __restrict__ lat, const unsigned short* __restrict__ W1T,
    const float* __restrict__ b1, unsigned short* __restrict__ Ab,
    unsigned short* __restrict__ P, int nNodes)
{
    __shared__ unsigned char w1lds[256 * 256];   // 64 KiB, swizzled rows of 256B

    const int wave = threadIdx.x >> 6;
    const int lane = threadIdx.x & 63;
    const int lg = lane >> 4, lr = lane & 15;
    const int mbase = blockIdx.x * 128 + wave * 32;

    // ---- stage W1T -> LDS (coalesced 16B chunks, XOR-swizzled dest) ----
#pragma unroll
    for (int p = 0; p < 16; ++p) {
        int g = p * 256 + threadIdx.x;       // global 16B-chunk id, 0..4095
        int row = g >> 4, c = g & 15;
        u32x4 v = *(const u32x4*)(W1T + (size_t)g * 8);
        *(u32x4*)(w1lds + row * 256 + ((c * 16) ^ ((row & 7) << 4))) = v;
    }

    f32x4 acc0[16], acc1[16];
#pragma unroll
    for (int i = 0; i < 16; ++i) {
        acc0[i] = (f32x4){0.f, 0.f, 0.f, 0.f};
        acc1[i] = (f32x4){0.f, 0.f, 0.f, 0.f};
    }

    const int r0 = mbase + lr;
    const int r1 = mbase + 16 + lr;
    const bool v0 = r0 < nNodes, v1 = r1 < nNodes;
    const float* p0 = lat + (size_t)(v0 ? r0 : (nNodes - 1)) * DIM;
    const float* p1 = lat + (size_t)(v1 ? r1 : (nNodes - 1)) * DIM;

    frag_u bl0[4], bl1[4];
#pragma unroll
    for (int ks = 0; ks < 4; ++ks) {
        f32x4 lo0 = *(const f32x4*)(p0 + ks * 32 + lg * 8);
        f32x4 hi0 = *(const f32x4*)(p0 + ks * 32 + lg * 8 + 4);
        f32x4 lo1 = *(const f32x4*)(p1 + ks * 32 + lg * 8);
        f32x4 hi1 = *(const f32x4*)(p1 + ks * 32 + lg * 8 + 4);
        bl0[ks].u[0] = cvt_pk_bf16(lo0[0], lo0[1]);
        bl0[ks].u[1] = cvt_pk_bf16(lo0[2], lo0[3]);
        bl0[ks].u[2] = cvt_pk_bf16(hi0[0], hi0[1]);
        bl0[ks].u[3] = cvt_pk_bf16(hi0[2], hi0[3]);
        bl1[ks].u[0] = cvt_pk_bf16(lo1[0], lo1[1]);
        bl1[ks].u[1] = cvt_pk_bf16(lo1[2], lo1[3]);
        bl1[ks].u[2] = cvt_pk_bf16(hi1[0], hi1[1]);
        bl1[ks].u[3] = cvt_pk_bf16(hi1[2], hi1[3]);
    }

    __syncthreads();   // staging complete

    const unsigned char* wbase = w1lds + lr * 256;   // row-part of lane addr
    const int xm = (lr & 7) << 4;
#pragma unroll
    for (int ks = 0; ks < 4; ++ks) {
        const int co = (ks * 64) | (lg * 16);        // chunk offset in row
        const unsigned char* wk = wbase + (co ^ xm); // swizzled lane base
#pragma unroll
        for (int nt = 0; nt < 16; ++nt) {
            fragAB af = *(const fragAB*)(wk + nt * 4096);   // imm-foldable
            acc0[nt] = __builtin_amdgcn_mfma_f32_16x16x32_bf16(af, bl0[ks].s, acc0[nt], 0, 0, 0);
            acc1[nt] = __builtin_amdgcn_mfma_f32_16x16x32_bf16(af, bl1[ks].s, acc1[nt], 0, 0, 0);
        }
    }

    if (v0) {
        unsigned short* arow = Ab + (size_t)r0 * DIM;
        unsigned short* prow = P  + (size_t)r0 * 256;
#pragma unroll
        for (int nt = 0; nt < 8; ++nt) {
            float4 bv = *(const float4*)(b1 + nt * 16 + lg * 4);
            uint2 pk;
            pk.x = cvt_pk_bf16(acc0[nt][0] + bv.x, acc0[nt][1] + bv.y);
            pk.y = cvt_pk_bf16(acc0[nt][2] + bv.z, acc0[nt][3] + bv.w);
            *(uint2*)(arow + nt * 16 + lg * 4) = pk;
        }
#pragma unroll
        for (int nt = 8; nt < 16; ++nt) {
            uint2 pk;
            pk.x = cvt_pk_bf16(acc0[nt][0], acc0[nt][1]);
            pk.y = cvt_pk_bf16(acc0[nt][2], acc0[nt][3]);
            *(uint2*)(prow + (nt - 8) * 16 + lg * 4) = pk;
        }
#pragma unroll
        for (int ks = 0; ks < 4; ++ks)
            *(fragAB*)(prow + DIM + ks * 32 + lg * 8) = bl0[ks].s;
    }
    if (v1) {
        unsigned short* arow = Ab + (size_t)r1 * DIM;
        unsigned short* prow = P  + (size_t)r1 * 256;
#pragma unroll
        for (int nt = 0; nt < 8; ++nt) {
            float4 bv = *(const float4*)(b1 + nt * 16 + lg * 4);
            uint2 pk;
            pk.x = cvt_pk_bf16(acc1[nt][0] + bv.x, acc1[nt][1] + bv.y);
            pk.y = cvt_pk_bf16(acc1[nt][2] + bv.z, acc1[nt][3] + bv.w);
            *(uint2*)(arow + nt * 16 + lg * 4) = pk;
        }
#pragma unroll
        for (int nt = 8; nt < 16; ++nt) {
            uint2 pk;
            pk.x = cvt_pk_bf16(acc1[nt][0], acc1[nt][1]);
            pk.y = cvt_pk_bf16(acc1[nt][2], acc1[nt][3]);
            *(uint2*)(prow + (nt - 8) * 16 + lg * 4) = pk;
        }
#pragma unroll
        for (int ks = 0; ks < 4; ++ks)
            *(fragAB*)(prow + DIM + ks * 32 + lg * 8) = bl1[ks].s;
    }
}

// ---------------------------------------------------------------------------
// Phase 2: one wave per node. Scores via MFMA (W2 replicated over B-cols),
// exp 4/lane + butterfly distribution, weighted aggregation of lat rows.
// Gather-service-bound floor (R6 MLP-doubling test: flat; bytes compulsory
// at bf16 precision; 4 rounds pinned at ~112.7us / 387MB).
// ---------------------------------------------------------------------------
__global__ __launch_bounds__(256) void na_score_agg(
    const int* __restrict__ nbr, const unsigned short* __restrict__ Ab,
    const unsigned short* __restrict__ Pu, const unsigned int* __restrict__ P32,
    const unsigned short* __restrict__ W2b, float* __restrict__ out, int nNodes)
{
    const int wave = threadIdx.x >> 6;
    const int lane = threadIdx.x & 63;
    const int lg = lane >> 4, lr = lane & 15;
    const int n = blockIdx.x * 4 + wave;
    if (n >= nNodes) return;

    const int jl = nbr[n * KNB + lr];          // lane's neighbor (k = lr)

    // B-half gathers: lane reads 16B of row j_lr per ks (A-frag layout for H)
    frag_u fB[4];
    const unsigned short* Pj = Pu + (size_t)jl * 256;
#pragma unroll
    for (int ks = 0; ks < 4; ++ks)
        fB[ks].s = *(const fragAB*)(Pj + ks * 32 + lg * 8);

    // lat-half gathers: lane owns dims (2l,2l+1), loop over k
    unsigned bL[KNB];
#pragma unroll
    for (int k = 0; k < KNB; ++k) {
        int j = __shfl(jl, k);
        bL[k] = P32[(size_t)j * 128 + 64 + lane];
    }

    // own A row + replicated-W2 B-frags (cache-hot)
    frag_u fA[4]; fragAB fW[4];
    const unsigned short* An = Ab + (size_t)n * DIM;
#pragma unroll
    for (int ks = 0; ks < 4; ++ks) {
        fA[ks].s = *(const fragAB*)(An + ks * 32 + lg * 8);
        fW[ks]   = *(const fragAB*)(W2b + ks * 32 + lg * 8);
    }

    // H build (bf16) + MFMA score chain
    f32x4 accS = (f32x4){0.f, 0.f, 0.f, 0.f};
#pragma unroll
    for (int ks = 0; ks < 4; ++ks) {
        u32x4 alo = fA[ks].u << 16, ahi = fA[ks].u & 0xffff0000u;
        u32x4 blo = fB[ks].u << 16, bhi = fB[ks].u & 0xffff0000u;
        frag_u h;
#pragma unroll
        for (int p = 0; p < 4; ++p) {
            float h0 = fmaxf(__uint_as_float(alo[p]) + __uint_as_float(blo[p]), 0.f);
            float h1 = fmaxf(__uint_as_float(ahi[p]) + __uint_as_float(bhi[p]), 0.f);
            h.u[p] = cvt_pk_bf16(h0, h1);
        }
        accS = __builtin_amdgcn_mfma_f32_16x16x32_bf16(h.s, fW[ks], accS, 0, 0, 0);
    }
    // lane holds S[lg*4+r] in accS[r] (replicated across lr)

    // softmax: global max, 4 exps per lane, distribute e across lg groups
    float m = fmaxf(fmaxf(accS[0], accS[1]), fmaxf(accS[2], accS[3]));
    m = fmaxf(m, __shfl_xor(m, 16));
    m = fmaxf(m, __shfl_xor(m, 32));

    float e4[4];
#pragma unroll
    for (int r = 0; r < 4; ++r) e4[r] = __expf(accS[r] - m);

    float sum = e4[0] + e4[1] + e4[2] + e4[3];
    sum += __shfl_xor(sum, 16);
    sum += __shfl_xor(sum, 32);
    const float inv = 1.f / sum;

    const bool hi1 = lg & 1, hi2 = lg & 2;
    float o4[4];
#pragma unroll
    for (int r = 0; r < 4; ++r) o4[r] = __shfl_xor(e4[r], 16);
    float v8[8];
#pragma unroll
    for (int r = 0; r < 4; ++r) {
        v8[r]     = hi1 ? o4[r] : e4[r];
        v8[4 + r] = hi1 ? e4[r] : o4[r];
    }
    float o8[8];
#pragma unroll
    for (int i = 0; i < 8; ++i) o8[i] = __shfl_xor(v8[i], 32);
    float e[KNB];
#pragma unroll
    for (int i = 0; i < 8; ++i) {
        e[i]     = hi2 ? o8[i] : v8[i];
        e[8 + i] = hi2 ? v8[i] : o8[i];
    }

    // weighted aggregation
    float o0 = 0.f, o1 = 0.f;
#pragma unroll
    for (int k = 0; k < KNB; ++k) {
        o0 += e[k] * bflo(bL[k]);
        o1 += e[k] * bfhi(bL[k]);
    }

    float2 o; o.x = o0 * inv; o.y = o1 * inv;
    *(float2*)(out + (size_t)n * DIM + 2 * lane) = o;
}

// ---------------------------------------------------------------------------
// Fallback (workspace too small): direct computation, one wave/node.
// ---------------------------------------------------------------------------
__global__ __launch_bounds__(256) void na_naive(
    const float* __restrict__ lat, const int* __restrict__ nbr,
    const float* __restrict__ W1, const float* __restrict__ b1,
    const float* __restrict__ W2, float* __restrict__ out, int nNodes)
{
    const int wave = threadIdx.x >> 6;
    const int lane = threadIdx.x & 63;
    const int n = blockIdx.x * 4 + wave;
    if (n >= nNodes) return;

    const int d0 = lane, d1 = lane + 64;
    const float w20 = W2[d0];
    const float w21 = W2[d1];
    const float c0 = lat[(size_t)n * DIM + d0];
    const float c1 = lat[(size_t)n * DIM + d1];

    float a0 = b1[d0], a1 = b1[d1];
    for (int r = 0; r < DIM; ++r) {
        float cv = (r < 64) ? __shfl(c0, r) : __shfl(c1, r - 64);
        a0 += cv * W1[(size_t)r * DIM + d0];
        a1 += cv * W1[(size_t)r * DIM + d1];
    }

    const int jl = nbr[n * KNB + (lane & 15)];
    float s[KNB], nl0[KNB], nl1[KNB];

    for (int k = 0; k < KNB; ++k) {
        int j = __shfl(jl, k);
        float l0 = lat[(size_t)j * DIM + d0];
        float l1 = lat[(size_t)j * DIM + d1];
        nl0[k] = l0; nl1[k] = l1;
        float h0 = a0, h1 = a1;
        for (int r = 0; r < DIM; ++r) {
            float nv = (r < 64) ? __shfl(l0, r) : __shfl(l1, r - 64);
            h0 += nv * W1[(size_t)(DIM + r) * DIM + d0];
            h1 += nv * W1[(size_t)(DIM + r) * DIM + d1];
        }
        h0 = fmaxf(h0, 0.f);
        h1 = fmaxf(h1, 0.f);
        float p = h0 * w20 + h1 * w21;
#pragma unroll
        for (int off = 32; off; off >>= 1) p += __shfl_xor(p, off);
        s[k] = p;
    }

    float m = s[0];
#pragma unroll
    for (int k = 1; k < KNB; ++k) m = fmaxf(m, s[k]);
    float sum = 0.f;
#pragma unroll
    for (int k = 0; k < KNB; ++k) { s[k] = expf(s[k] - m); sum += s[k]; }
    float inv = 1.f / sum;

    float o0 = 0.f, o1 = 0.f;
#pragma unroll
    for (int k = 0; k < KNB; ++k) { o0 += s[k] * nl0[k]; o1 += s[k] * nl1[k]; }

    out[(size_t)n * DIM + d0] = o0 * inv;
    out[(size_t)n * DIM + d1] = o1 * inv;
}

extern "C" void kernel_launch(void* const* d_in, const int* in_sizes, int n_in,
                              void* d_out, int out_size, void* d_ws, size_t ws_size,
                              hipStream_t stream)
{
    const float* lat = (const float*)d_in[0];
    const int*   nbr = (const int*)  d_in[1];
    const float* W1  = (const float*)d_in[2];
    const float* b1  = (const float*)d_in[3];
    const float* W2  = (const float*)d_in[4];
    // d_in[5] = b2: shift-invariant under softmax, unused.
    float* out = (float*)d_out;

    const int nNodes = in_sizes[0] / DIM;  // 100000
    const size_t bytesAb = (size_t)nNodes * DIM * sizeof(unsigned short); // 25.6 MB
    const size_t bytesP  = (size_t)nNodes * 256 * sizeof(unsigned short); // 51.2 MB
    const size_t bytesW  = (256 * DIM + DIM) * sizeof(unsigned short);    // 64.25 KiB

    if (ws_size >= bytesAb + bytesP + bytesW) {
        unsigned short* Ab  = (unsigned short*)d_ws;
        unsigned short* P   = (unsigned short*)((char*)d_ws + bytesAb);
        unsigned short* W1T = (unsigned short*)((char*)d_ws + bytesAb + bytesP);
        unsigned short* W2b = W1T + 256 * DIM;
        na_w1t<<<128, 256, 0, stream>>>(W1, W2, W1T, W2b);
        na_precompute_mfma<<<(nNodes + 127) / 128, 256, 0, stream>>>(lat, W1T, b1, Ab, P, nNodes);
        na_score_agg<<<(nNodes + 3) / 4, 256, 0, stream>>>(nbr, Ab, P, (const unsigned int*)P, W2b, out, nNodes);
    } else {
        na_naive<<<(nNodes + 3) / 4, 256, 0, stream>>>(lat, nbr, W1, b1, W2, out, nNodes);
    }
}